// Round 9
// baseline (365.626 us; speedup 1.0000x reference)
//
#include <hip/hip_runtime.h>
#include <stdint.h>

#define N_ROWS 4096
#define D_DIM  1024
#define ROWB   1024   // bytes per row in fp8
#define T_TEMP 0.15f

#define AS1 __attribute__((address_space(1)))
#define AS3 __attribute__((address_space(3)))

typedef float f32x4  __attribute__((ext_vector_type(4)));
typedef int   i32x4v __attribute__((ext_vector_type(4)));
typedef int   i32x8  __attribute__((ext_vector_type(8)));

__device__ __forceinline__ float wsum(float v) {
#pragma unroll
  for (int m = 32; m >= 1; m >>= 1) v += __shfl_xor(v, m, 64);
  return v;
}
__device__ __forceinline__ float wmax(float v) {
#pragma unroll
  for (int m = 32; m >= 1; m >>= 1) v = fmaxf(v, __shfl_xor(v, m, 64));
  return v;
}

// One WAVE per row (no barriers): norms, x.y dot (-> log pos), softmax-JS
// per-row term -> js[row], fp8-e4m3 casts into Bb = [x;y] (8192 x 1024).
// Zeroes rowsum.
__global__ __launch_bounds__(256) void prep_kernel(
    const float* __restrict__ x, const float* __restrict__ y,
    unsigned char* __restrict__ Bb, float* __restrict__ inv_n,
    float* __restrict__ logpos, float* __restrict__ js,
    float* __restrict__ rowsum) {
  if (threadIdx.x < 4) rowsum[blockIdx.x * 4 + threadIdx.x] = 0.0f;

  const int wid = threadIdx.x >> 6, lane = threadIdx.x & 63;
  const int row = blockIdx.x * 4 + wid;
  const float4* xp = (const float4*)(x + (size_t)row * D_DIM) + lane * 4;
  const float4* yp = (const float4*)(y + (size_t)row * D_DIM) + lane * 4;

  float xv[16], yv[16];
#pragma unroll
  for (int i = 0; i < 4; ++i) {
    float4 a = xp[i], b = yp[i];
    xv[i*4+0]=a.x; xv[i*4+1]=a.y; xv[i*4+2]=a.z; xv[i*4+3]=a.w;
    yv[i*4+0]=b.x; yv[i*4+1]=b.y; yv[i*4+2]=b.z; yv[i*4+3]=b.w;
  }

  float sx2=0.f, sy2=0.f, sxy=0.f, mx=-1e30f, my=-1e30f;
#pragma unroll
  for (int k = 0; k < 16; ++k) {
    sx2 = fmaf(xv[k], xv[k], sx2);
    sy2 = fmaf(yv[k], yv[k], sy2);
    sxy = fmaf(xv[k], yv[k], sxy);
    mx = fmaxf(mx, xv[k]); my = fmaxf(my, yv[k]);
  }
  sx2 = wsum(sx2); sy2 = wsum(sy2); sxy = wsum(sxy);
  mx = wmax(mx);  my = wmax(my);

  float ex[16], ey[16], sex=0.f, sey=0.f;
#pragma unroll
  for (int k = 0; k < 16; ++k) {
    ex[k] = __expf(xv[k] - mx); ey[k] = __expf(yv[k] - my);
    sex += ex[k]; sey += ey[k];
  }
  sex = wsum(sex); sey = wsum(sey);
  const float lsex = __logf(sex), lsey = __logf(sey);
  const float rsex = 1.f / sex,  rsey = 1.f / sey;

  float term = 0.f;
#pragma unroll
  for (int k = 0; k < 16; ++k) {
    float a = ex[k] * rsex, b = ey[k] * rsey;
    float lm = __logf(0.5f * (a + b));
    term += a * ((xv[k] - mx - lsex) - lm) + b * ((yv[k] - my - lsey) - lm);
  }
  term = wsum(term);

  if (lane == 0) {
    const float nx = sqrtf(sx2), ny = sqrtf(sy2);
    inv_n[row] = 1.f / nx;
    inv_n[N_ROWS + row] = 1.f / ny;
    logpos[row] = sxy / fmaxf(nx * ny, 1e-8f) / T_TEMP;  // ln(pos)
    js[row] = term;
  }

  int p[4], q[4];
#pragma unroll
  for (int w = 0; w < 4; ++w) {
    int v = 0;
    v = __builtin_amdgcn_cvt_pk_fp8_f32(xv[w*4+0], xv[w*4+1], v, false);
    v = __builtin_amdgcn_cvt_pk_fp8_f32(xv[w*4+2], xv[w*4+3], v, true);
    p[w] = v;
    int u = 0;
    u = __builtin_amdgcn_cvt_pk_fp8_f32(yv[w*4+0], yv[w*4+1], u, false);
    u = __builtin_amdgcn_cvt_pk_fp8_f32(yv[w*4+2], yv[w*4+3], u, true);
    q[w] = u;
  }
  *(int4*)(Bb + (size_t)row * ROWB + lane * 16) = make_int4(p[0], p[1], p[2], p[3]);
  *(int4*)(Bb + (size_t)(N_ROWS + row) * ROWB + lane * 16) = make_int4(q[0], q[1], q[2], q[3]);
}

// frag read (R2-verified): lane's 32 fp8 of row r at k = hi*32..hi*32+31;
// slots XOR-swizzled by row&7 on both sides, so order is k-correct.
__device__ __forceinline__ i32x8 frag8(const char* rowbase, int s0) {
  i32x4v p0 = *(const i32x4v*)(rowbase + s0 * 16);
  i32x4v p1 = *(const i32x4v*)(rowbase + (s0 ^ 1) * 16);
  i32x8 r;
  r[0]=p0[0]; r[1]=p0[1]; r[2]=p0[2]; r[3]=p0[3];
  r[4]=p1[0]; r[5]=p1[1]; r[6]=p1[2]; r[7]=p1[3];
  return r;
}

// ===== MX-fp8 (unit scales) symmetric fused GEMM, 128x128, 4 waves =====
// K=128 per tile (8 tiles, 16 barriers). LDS [row][128B], chunk-XOR by
// row&7 on both sides (R2-verified correct, ~4M conflicts tolerable).
// B-fragments JIT-loaded per n to keep VGPR <= 168 (3 waves/SIMD, 3
// blocks/CU with 32KB LDS) -- fixes R2's occupancy collapse.
#define GLL(src, dst) __builtin_amdgcn_global_load_lds((const AS1 void*)(src), (AS3 void*)(dst), 16, 0, 0)

__global__ __launch_bounds__(256, 3) void gemm_fused(
    const unsigned char* __restrict__ Bb, const float* __restrict__ inv_n,
    float* __restrict__ rowsum) {
  __shared__ __align__(16) char As[128 * 128];
  __shared__ __align__(16) char Bs[128 * 128];
  const int tid = threadIdx.x;
  const int wid = tid >> 6, lane = tid & 63;
  const int lo = lane & 15, hi = lane >> 4;

  int bi, bj;
  bool sym = false;
  {
    const int idx = blockIdx.x;
    if (idx < 1024) {
      bi = idx >> 5; bj = 32 + (idx & 31);
    } else {
      const int t = idx - 1024;
      int b = (int)((65.0 - sqrt((double)(4225 - 8 * t))) * 0.5);
      while ((b + 1) * (65 - (b + 1)) / 2 <= t) ++b;
      while (b * (65 - b) / 2 > t) --b;
      bi = b;
      bj = b + (t - b * (65 - b) / 2);
      sym = (bi != bj);
    }
  }
  const int grow0 = bi * 128;
  const int gcol0 = bj * 128;
  const int wrow = (wid >> 1) * 64, wcol = (wid & 1) * 64;

  f32x4 acc[4][4] = {};

  // staging (R2-verified): wave w covers rows {w*8 + l3 + 32i}; lane's 16B
  // chunk pre-swizzled by row&7 = l3; LDS dest linear (HW adds lane*16).
  const int l3 = lane >> 3;
  const int chunk = (lane & 7) ^ l3;
  const unsigned char* gA = Bb + (size_t)(grow0 + wid * 8 + l3) * ROWB + chunk * 16;
  const unsigned char* gB = Bb + (size_t)(gcol0 + wid * 8 + l3) * ROWB + chunk * 16;

  for (int kt = 0; kt < 8; ++kt) {
    __syncthreads();   // prior reads done before overwrite
#pragma unroll
    for (int i = 0; i < 4; ++i) {
      GLL(gA + (size_t)i * 32 * ROWB + kt * 128, As + i * 4096 + wid * 1024);
      GLL(gB + (size_t)i * 32 * ROWB + kt * 128, Bs + i * 4096 + wid * 1024);
    }
    __syncthreads();   // staging visible

    const int e = lo & 7;
    i32x8 af[4];
#pragma unroll
    for (int m = 0; m < 4; ++m)
      af[m] = frag8(As + (wrow + m * 16 + lo) * 128, (2 * hi) ^ e);
#pragma unroll
    for (int n = 0; n < 4; ++n) {
      const i32x8 bf = frag8(Bs + (wcol + n * 16 + lo) * 128, (2 * hi) ^ e);
#pragma unroll
      for (int m = 0; m < 4; ++m)
        acc[m][n] = __builtin_amdgcn_mfma_scale_f32_16x16x128_f8f6f4(
            af[m], bf, acc[m][n], 0, 0,              // cbsz=fp8, blgp=fp8
            0, 0x7F7F7F7F, 0, 0x7F7F7F7F);           // unit E8M0 scales
    }
  }

  // epilogue: scale -> exp2 -> mask diag -> row-reduce (+col-reduce if sym)
  const float C = 1.4426950408889634f / T_TEMP;   // log2(e)/T
  float invc[4], invr[4][4];
#pragma unroll
  for (int n = 0; n < 4; ++n)
    invc[n] = inv_n[gcol0 + wcol + n * 16 + lo] * C;
#pragma unroll
  for (int m = 0; m < 4; ++m)
#pragma unroll
    for (int r = 0; r < 4; ++r)
      invr[m][r] = inv_n[grow0 + wrow + m * 16 + hi * 4 + r];

  float rp[4][4] = {};
  float cp[4] = {};
#pragma unroll
  for (int m = 0; m < 4; ++m)
#pragma unroll
    for (int n = 0; n < 4; ++n)
#pragma unroll
      for (int r = 0; r < 4; ++r) {
        const int i = grow0 + wrow + m * 16 + hi * 4 + r;
        const int j = gcol0 + wcol + n * 16 + lo;
        float e2 = exp2f(acc[m][n][r] * invr[m][r] * invc[n]);
        if (j == i || j == i + N_ROWS) e2 = 0.0f;
        rp[m][r] += e2;
        cp[n] += e2;
      }

#pragma unroll
  for (int m = 0; m < 4; ++m)
#pragma unroll
    for (int r = 0; r < 4; ++r) {
      float v = rp[m][r];
      v += __shfl_xor(v, 1, 16);
      v += __shfl_xor(v, 2, 16);
      v += __shfl_xor(v, 4, 16);
      v += __shfl_xor(v, 8, 16);
      if (lo == 0)
        atomicAdd(&rowsum[grow0 + wrow + m * 16 + hi * 4 + r], v);
    }

  if (sym) {
#pragma unroll
    for (int n = 0; n < 4; ++n) {
      float v = cp[n];
      v += __shfl_xor(v, 16, 64);
      v += __shfl_xor(v, 32, 64);
      if (hi == 0)
        atomicAdd(&rowsum[gcol0 + wcol + n * 16 + lo], v);
    }
  }
}

// Single block: cumsum(rowsum) -> sum(log(neg) - logpos) + sum(js) -> out[0]
__global__ __launch_bounds__(256) void final_kernel(
    const float* __restrict__ rowsum, const float* __restrict__ logpos,
    const float* __restrict__ js, float* __restrict__ out) {
  __shared__ float scan[256];
  __shared__ double ds[4];
  __shared__ float fs[4];
  const int tid = threadIdx.x;
  float loc[16];
  float run = 0.f, jl = 0.f;
#pragma unroll
  for (int k = 0; k < 16; ++k) {
    loc[k] = rowsum[tid * 16 + k];
    run += loc[k];
    jl += js[tid * 16 + k];
  }
  scan[tid] = run;
  __syncthreads();
  for (int d = 1; d < 256; d <<= 1) {
    float add = (tid >= d) ? scan[tid - d] : 0.0f;
    __syncthreads();
    scan[tid] += add;
    __syncthreads();
  }
  float c = scan[tid] - run;  // exclusive prefix
  double acc = 0.0;
#pragma unroll
  for (int k = 0; k < 16; ++k) {
    c += loc[k];
    acc += (double)(logf(c) - logpos[tid * 16 + k]);
  }
#pragma unroll
  for (int m = 32; m >= 1; m >>= 1) {
    acc += __shfl_xor(acc, m, 64);
    jl  += __shfl_xor(jl, m, 64);
  }
  if ((tid & 63) == 0) { ds[tid >> 6] = acc; fs[tid >> 6] = jl; }
  __syncthreads();
  if (tid == 0) {
    const double nce = ds[0] + ds[1] + ds[2] + ds[3];
    const double jst = (double)(fs[0] + fs[1] + fs[2] + fs[3]);
    out[0] = (float)(nce + jst / (2.0 * N_ROWS));
  }
}

extern "C" void kernel_launch(void* const* d_in, const int* in_sizes, int n_in,
                              void* d_out, int out_size, void* d_ws, size_t ws_size,
                              hipStream_t stream) {
  const float* x = (const float*)d_in[0];
  const float* y = (const float*)d_in[1];
  float* out = (float*)d_out;

  char* ws = (char*)d_ws;
  unsigned char* Bb = (unsigned char*)ws;                  // [8192][1024] fp8, 8 MB
  float* inv_n  = (float*)(ws + (size_t)8 * 1024 * 1024);  // 8192
  float* logpos = inv_n + 8192;                            // 4096
  float* rowsum = logpos + 4096;                           // 4096
  float* js     = rowsum + 4096;                           // 4096

  prep_kernel<<<N_ROWS / 4, 256, 0, stream>>>(x, y, Bb, inv_n, logpos, js, rowsum);
  gemm_fused<<<1552, 256, 0, stream>>>(Bb, inv_n, rowsum);
  final_kernel<<<1, 256, 0, stream>>>(rowsum, logpos, js, out);
}

// Round 10
// 66.410 us; speedup vs baseline: 5.5056x; 5.5056x over previous
//
#include <hip/hip_runtime.h>
#include <stdint.h>

#define N_ROWS 4096
#define D_DIM  1024
#define ROWB   1024   // bytes per row in fp8
#define T_TEMP 0.15f

#define AS1 __attribute__((address_space(1)))
#define AS3 __attribute__((address_space(3)))

typedef float f32x4  __attribute__((ext_vector_type(4)));
typedef int   i32x4v __attribute__((ext_vector_type(4)));

__device__ __forceinline__ float wsum(float v) {
#pragma unroll
  for (int m = 32; m >= 1; m >>= 1) v += __shfl_xor(v, m, 64);
  return v;
}
__device__ __forceinline__ float wmax(float v) {
#pragma unroll
  for (int m = 32; m >= 1; m >>= 1) v = fmaxf(v, __shfl_xor(v, m, 64));
  return v;
}

// One WAVE per row (no barriers): norms, x.y dot (-> log pos), softmax-JS
// per-row term -> js[row]. fp8-e4m3 casts stored INTERLEAVED into
// Bb = [x;y]: within each 64B K-group, 16B pair h = (kk0 chunk h | kk1
// chunk h) (8B each), so the GEMM can fetch both K=32 sub-operands with
// one b128. Zeroes rowsum.
__global__ __launch_bounds__(256) void prep_kernel(
    const float* __restrict__ x, const float* __restrict__ y,
    unsigned char* __restrict__ Bb, float* __restrict__ inv_n,
    float* __restrict__ logpos, float* __restrict__ js,
    float* __restrict__ rowsum) {
  if (threadIdx.x < 4) rowsum[blockIdx.x * 4 + threadIdx.x] = 0.0f;

  const int wid = threadIdx.x >> 6, lane = threadIdx.x & 63;
  const int row = blockIdx.x * 4 + wid;
  const float4* xp = (const float4*)(x + (size_t)row * D_DIM) + lane * 4;
  const float4* yp = (const float4*)(y + (size_t)row * D_DIM) + lane * 4;

  float xv[16], yv[16];
#pragma unroll
  for (int i = 0; i < 4; ++i) {
    float4 a = xp[i], b = yp[i];
    xv[i*4+0]=a.x; xv[i*4+1]=a.y; xv[i*4+2]=a.z; xv[i*4+3]=a.w;
    yv[i*4+0]=b.x; yv[i*4+1]=b.y; yv[i*4+2]=b.z; yv[i*4+3]=b.w;
  }

  float sx2=0.f, sy2=0.f, sxy=0.f, mx=-1e30f, my=-1e30f;
#pragma unroll
  for (int k = 0; k < 16; ++k) {
    sx2 = fmaf(xv[k], xv[k], sx2);
    sy2 = fmaf(yv[k], yv[k], sy2);
    sxy = fmaf(xv[k], yv[k], sxy);
    mx = fmaxf(mx, xv[k]); my = fmaxf(my, yv[k]);
  }
  sx2 = wsum(sx2); sy2 = wsum(sy2); sxy = wsum(sxy);
  mx = wmax(mx);  my = wmax(my);

  float ex[16], ey[16], sex=0.f, sey=0.f;
#pragma unroll
  for (int k = 0; k < 16; ++k) {
    ex[k] = __expf(xv[k] - mx); ey[k] = __expf(yv[k] - my);
    sex += ex[k]; sey += ey[k];
  }
  sex = wsum(sex); sey = wsum(sey);
  const float lsex = __logf(sex), lsey = __logf(sey);
  const float rsex = 1.f / sex,  rsey = 1.f / sey;

  float term = 0.f;
#pragma unroll
  for (int k = 0; k < 16; ++k) {
    float a = ex[k] * rsex, b = ey[k] * rsey;
    float lm = __logf(0.5f * (a + b));
    term += a * ((xv[k] - mx - lsex) - lm) + b * ((yv[k] - my - lsey) - lm);
  }
  term = wsum(term);

  if (lane == 0) {
    const float nx = sqrtf(sx2), ny = sqrtf(sy2);
    inv_n[row] = 1.f / nx;
    inv_n[N_ROWS + row] = 1.f / ny;
    logpos[row] = sxy / fmaxf(nx * ny, 1e-8f) / T_TEMP;  // ln(pos)
    js[row] = term;
  }

  int p[4], q[4];
#pragma unroll
  for (int w = 0; w < 4; ++w) {
    int v = 0;
    v = __builtin_amdgcn_cvt_pk_fp8_f32(xv[w*4+0], xv[w*4+1], v, false);
    v = __builtin_amdgcn_cvt_pk_fp8_f32(xv[w*4+2], xv[w*4+3], v, true);
    p[w] = v;
    int u = 0;
    u = __builtin_amdgcn_cvt_pk_fp8_f32(yv[w*4+0], yv[w*4+1], u, false);
    u = __builtin_amdgcn_cvt_pk_fp8_f32(yv[w*4+2], yv[w*4+3], u, true);
    q[w] = u;
  }
  // interleaved store: lane's 16 bytes = chunks (2l, 2l+1) of group l>>2,
  // kk = (l&3)>>1, h0 = (l&3 & 1)*2; dest = group*64 + h*16 + kk*8.
  const int ktp = lane >> 2;
  const int lq  = lane & 3;
  const int kkb = lq >> 1;
  const int h0  = (lq & 1) * 2;
  {
    char* ob = (char*)Bb + (size_t)row * ROWB + ktp * 64 + kkb * 8 + h0 * 16;
    *(int2*)(ob)      = make_int2(p[0], p[1]);
    *(int2*)(ob + 16) = make_int2(p[2], p[3]);
    char* oy = (char*)Bb + (size_t)(N_ROWS + row) * ROWB + ktp * 64 + kkb * 8 + h0 * 16;
    *(int2*)(oy)      = make_int2(q[0], q[1]);
    *(int2*)(oy + 16) = make_int2(q[2], q[3]);
  }
}

// ===== fp8 symmetric fused GEMM, 128x128, 4 waves, BK=128, b128 frags =====
// Bb rows are interleaved (see prep). LDS [128 rows][128B]; 16B slot sigma
// of row r holds (group gi = (sigma>>2)^(r&1), pair h = (sigma&3)^((r>>1)&3))
// -- staging pre-swizzles the 16B global source (contiguous, GLL-legal);
// fragment read inverts the same XOR. Every b128 8-lane phase hits 8
// distinct bank-quads (enumerated) -> expect ~0 conflicts.
// 8 K-tiles x 2 barriers = 16 barriers; 64 MFMA/wave between pairs.
#define GLL(src, dst) __builtin_amdgcn_global_load_lds((const AS1 void*)(src), (AS3 void*)(dst), 16, 0, 0)

__global__ __launch_bounds__(256, 3) void gemm_fused(
    const unsigned char* __restrict__ Bb, const float* __restrict__ inv_n,
    float* __restrict__ rowsum) {
  __shared__ __align__(16) char As[128 * 128];
  __shared__ __align__(16) char Bs[128 * 128];
  const int tid = threadIdx.x;
  const int wid = tid >> 6, lane = tid & 63;
  const int lo = lane & 15, hi = lane >> 4;

  int bi, bj;
  bool sym = false;
  {
    const int idx = blockIdx.x;
    if (idx < 1024) {
      bi = idx >> 5; bj = 32 + (idx & 31);
    } else {
      const int t = idx - 1024;
      int b = (int)((65.0 - sqrt((double)(4225 - 8 * t))) * 0.5);
      while ((b + 1) * (65 - (b + 1)) / 2 <= t) ++b;
      while (b * (65 - b) / 2 > t) --b;
      bi = b;
      bj = b + (t - b * (65 - b) / 2);
      sym = (bi != bj);
    }
  }
  const int grow0 = bi * 128;
  const int gcol0 = bj * 128;
  const int wrow = (wid >> 1) * 64, wcol = (wid & 1) * 64;

  f32x4 acc[4][4] = {};

  // staging: call q covers rows q*32..q*32+31; thread t -> row q*32 + (t>>3),
  // LDS slot t&7. Source slot pre-swizzle: gi = (s>>2)^(row&1),
  // h = (s&3)^((row>>1)&3); both depend only on srow = t>>3.
  const int srow = tid >> 3;
  const int s    = tid & 7;
  const int soff = (((s >> 2) ^ (srow & 1)) << 6) |
                   ((((s & 3) ^ ((srow >> 1) & 3))) << 4);
  const char* gA = (const char*)Bb + (size_t)(grow0 + srow) * ROWB + soff;
  const char* gB = (const char*)Bb + (size_t)(gcol0 + srow) * ROWB + soff;
  char* dA = As + tid * 16;
  char* dB = Bs + tid * 16;

  // fragment read swizzle pieces (row == lo mod 16)
  const int hsw = hi ^ ((lo >> 1) & 3);
  const int gsw = lo & 1;

  union U { i32x4v v; long l[2]; };

  for (int kt = 0; kt < 8; ++kt) {
    __syncthreads();   // prior reads done before overwrite
#pragma unroll
    for (int q = 0; q < 4; ++q) {
      GLL(gA + (size_t)q * 32 * ROWB + kt * 128, dA + q * 4096);
      GLL(gB + (size_t)q * 32 * ROWB + kt * 128, dB + q * 4096);
    }
    __syncthreads();   // staging visible

#pragma unroll
    for (int gi = 0; gi < 2; ++gi) {
      const int slot = ((gi ^ gsw) << 2) | hsw;   // 16B slot within 128B row
      U a[4];
#pragma unroll
      for (int m = 0; m < 4; ++m)
        a[m].v = *(const i32x4v*)(As + (wrow + m * 16 + lo) * 128 + slot * 16);
#pragma unroll
      for (int n = 0; n < 4; ++n) {
        U bv;
        bv.v = *(const i32x4v*)(Bs + (wcol + n * 16 + lo) * 128 + slot * 16);
#pragma unroll
        for (int m = 0; m < 4; ++m) {
          acc[m][n] = __builtin_amdgcn_mfma_f32_16x16x32_fp8_fp8(
              a[m].l[0], bv.l[0], acc[m][n], 0, 0, 0);
          acc[m][n] = __builtin_amdgcn_mfma_f32_16x16x32_fp8_fp8(
              a[m].l[1], bv.l[1], acc[m][n], 0, 0, 0);
        }
      }
    }
  }

  // epilogue: scale -> exp2 -> mask diag -> row-reduce (+col-reduce if sym)
  const float C = 1.4426950408889634f / T_TEMP;   // log2(e)/T
  float invc[4], invr[4][4];
#pragma unroll
  for (int n = 0; n < 4; ++n)
    invc[n] = inv_n[gcol0 + wcol + n * 16 + lo] * C;
#pragma unroll
  for (int m = 0; m < 4; ++m)
#pragma unroll
    for (int r = 0; r < 4; ++r)
      invr[m][r] = inv_n[grow0 + wrow + m * 16 + hi * 4 + r];

  float rp[4][4] = {};
  float cp[4] = {};
#pragma unroll
  for (int m = 0; m < 4; ++m)
#pragma unroll
    for (int n = 0; n < 4; ++n)
#pragma unroll
      for (int r = 0; r < 4; ++r) {
        const int i = grow0 + wrow + m * 16 + hi * 4 + r;
        const int j = gcol0 + wcol + n * 16 + lo;
        float e2 = exp2f(acc[m][n][r] * invr[m][r] * invc[n]);
        if (j == i || j == i + N_ROWS) e2 = 0.0f;
        rp[m][r] += e2;
        cp[n] += e2;
      }

#pragma unroll
  for (int m = 0; m < 4; ++m)
#pragma unroll
    for (int r = 0; r < 4; ++r) {
      float v = rp[m][r];
      v += __shfl_xor(v, 1, 16);
      v += __shfl_xor(v, 2, 16);
      v += __shfl_xor(v, 4, 16);
      v += __shfl_xor(v, 8, 16);
      if (lo == 0)
        atomicAdd(&rowsum[grow0 + wrow + m * 16 + hi * 4 + r], v);
    }

  if (sym) {
#pragma unroll
    for (int n = 0; n < 4; ++n) {
      float v = cp[n];
      v += __shfl_xor(v, 16, 64);
      v += __shfl_xor(v, 32, 64);
      if (hi == 0)
        atomicAdd(&rowsum[gcol0 + wcol + n * 16 + lo], v);
    }
  }
}

// Single block: cumsum(rowsum) -> sum(log(neg) - logpos) + sum(js) -> out[0]
__global__ __launch_bounds__(256) void final_kernel(
    const float* __restrict__ rowsum, const float* __restrict__ logpos,
    const float* __restrict__ js, float* __restrict__ out) {
  __shared__ float scan[256];
  __shared__ double ds[4];
  __shared__ float fs[4];
  const int tid = threadIdx.x;
  float loc[16];
  float run = 0.f, jl = 0.f;
#pragma unroll
  for (int k = 0; k < 16; ++k) {
    loc[k] = rowsum[tid * 16 + k];
    run += loc[k];
    jl += js[tid * 16 + k];
  }
  scan[tid] = run;
  __syncthreads();
  for (int d = 1; d < 256; d <<= 1) {
    float add = (tid >= d) ? scan[tid - d] : 0.0f;
    __syncthreads();
    scan[tid] += add;
    __syncthreads();
  }
  float c = scan[tid] - run;  // exclusive prefix
  double acc = 0.0;
#pragma unroll
  for (int k = 0; k < 16; ++k) {
    c += loc[k];
    acc += (double)(logf(c) - logpos[tid * 16 + k]);
  }
#pragma unroll
  for (int m = 32; m >= 1; m >>= 1) {
    acc += __shfl_xor(acc, m, 64);
    jl  += __shfl_xor(jl, m, 64);
  }
  if ((tid & 63) == 0) { ds[tid >> 6] = acc; fs[tid >> 6] = jl; }
  __syncthreads();
  if (tid == 0) {
    const double nce = ds[0] + ds[1] + ds[2] + ds[3];
    const double jst = (double)(fs[0] + fs[1] + fs[2] + fs[3]);
    out[0] = (float)(nce + jst / (2.0 * N_ROWS));
  }
}

extern "C" void kernel_launch(void* const* d_in, const int* in_sizes, int n_in,
                              void* d_out, int out_size, void* d_ws, size_t ws_size,
                              hipStream_t stream) {
  const float* x = (const float*)d_in[0];
  const float* y = (const float*)d_in[1];
  float* out = (float*)d_out;

  char* ws = (char*)d_ws;
  unsigned char* Bb = (unsigned char*)ws;                  // [8192][1024] fp8 interleaved, 8 MB
  float* inv_n  = (float*)(ws + (size_t)8 * 1024 * 1024);  // 8192
  float* logpos = inv_n + 8192;                            // 4096
  float* rowsum = logpos + 4096;                           // 4096
  float* js     = rowsum + 4096;                           // 4096

  prep_kernel<<<N_ROWS / 4, 256, 0, stream>>>(x, y, Bb, inv_n, logpos, js, rowsum);
  gemm_fused<<<1552, 256, 0, stream>>>(Bb, inv_n, rowsum);
  final_kernel<<<1, 256, 0, stream>>>(rowsum, logpos, js, out);
}